// Round 11
// baseline (30.230 us; speedup 1.0000x reference)
//
#include <hip/hip_runtime.h>
#include <climits>

// B=256 rows, N=65536, half=32768.
constexpr int HALF  = 32768;
constexpr int TPB   = 256;
constexpr int CHUNK = 2048;              // elements per half-stream per block
constexpr int NCHNK = HALF / CHUNK;      // 16 chunks per row
constexpr float THRESH = 0.01f;

// ---------------- Kernel A: streaming pass (proven R6 body) ----------------
// Also zeroes out[0] (block (0,0) only) so kernel B can accumulate into it —
// stream order guarantees the zero lands before any of B's atomics.
__global__ __launch_bounds__(TPB)
void main_kernel(const float* __restrict__ pred, const float* __restrict__ label,
                 float* __restrict__ part_sum, int4* __restrict__ part_idx,
                 float* __restrict__ out)
{
    const int chunk = blockIdx.x, row = blockIdx.y;
    const int t = threadIdx.x, wave = t >> 6, lane = t & 63;

    if (chunk == 0 && row == 0 && t == 0) out[0] = 0.0f;

    const size_t rb4 = (size_t)row * (size_t)(2 * HALF / 4);
    const float4* lr4 = (const float4*)label + rb4;
    const float4* pr4 = (const float4*)pred + rb4;

    const int v0 = chunk * (CHUNK / 4) + t;          // coalesced: lane l -> float4 l
    const int v1 = v0 + TPB;
    const int H4 = HALF / 4;

    float4 a0 = lr4[v0],      a1 = lr4[v1];
    float4 b0 = lr4[v0 + H4], b1 = lr4[v1 + H4];
    float4 p0 = pr4[v0],      p1 = pr4[v1];
    float4 q0 = pr4[v0 + H4], q1 = pr4[v1 + H4];

    float sum = 0.f;
    int minr = INT_MAX, maxr = -1, mini = INT_MAX, maxi = -1;

#define STEP(ax, bx, px, qx, idx)                                 \
    {                                                             \
        float dr = (px) - (ax), di = (qx) - (bx);                 \
        float lint = (ax) * (ax) + (bx) * (bx);                   \
        float pint = (px) * (px) + (qx) * (qx);                   \
        float dd = pint - lint;                                   \
        sum += dr * dr + di * di + 50.f * dd * dd;                \
        if (fabsf(ax) > THRESH) {                                 \
            minr = min(minr, (idx)); maxr = max(maxr, (idx));     \
        }                                                         \
        if (fabsf(bx) > THRESH) {                                 \
            mini = min(mini, (idx)); maxi = max(maxi, (idx));     \
        }                                                         \
    }
    {
        const int base = v0 * 4;
        STEP(a0.x, b0.x, p0.x, q0.x, base + 0)
        STEP(a0.y, b0.y, p0.y, q0.y, base + 1)
        STEP(a0.z, b0.z, p0.z, q0.z, base + 2)
        STEP(a0.w, b0.w, p0.w, q0.w, base + 3)
    }
    {
        const int base = v1 * 4;
        STEP(a1.x, b1.x, p1.x, q1.x, base + 0)
        STEP(a1.y, b1.y, p1.y, q1.y, base + 1)
        STEP(a1.z, b1.z, p1.z, q1.z, base + 2)
        STEP(a1.w, b1.w, p1.w, q1.w, base + 3)
    }
#undef STEP

    #pragma unroll
    for (int off = 32; off > 0; off >>= 1) {
        sum += __shfl_down(sum, off);
        minr = min(minr, __shfl_down(minr, off));
        maxr = max(maxr, __shfl_down(maxr, off));
        mini = min(mini, __shfl_down(mini, off));
        maxi = max(maxi, __shfl_down(maxi, off));
    }

    __shared__ float s_sum[4];
    __shared__ int   s_idx[4][4];
    if (lane == 0) {
        s_sum[wave] = sum;
        s_idx[wave][0] = minr; s_idx[wave][1] = maxr;
        s_idx[wave][2] = mini; s_idx[wave][3] = maxi;
    }
    __syncthreads();
    if (t == 0) {
        float S = 0.f; int mr = INT_MAX, Mr = -1, mi = INT_MAX, Mi = -1;
        #pragma unroll
        for (int w = 0; w < 4; ++w) {
            S += s_sum[w];
            mr = min(mr, s_idx[w][0]); Mr = max(Mr, s_idx[w][1]);
            mi = min(mi, s_idx[w][2]); Mi = max(Mi, s_idx[w][3]);
        }
        const int slot = row * NCHNK + chunk;        // [row][chunk]
        part_sum[slot] = S;
        part_idx[slot] = make_int4(mr, Mr, mi, Mi);
    }
}

// ---------------- Kernel B: per-row edges + direct atomic accumulate ----------------
__global__ __launch_bounds__(TPB)
void edge_kernel(const float* __restrict__ pred, const float* __restrict__ label,
                 const float* __restrict__ part_sum, const int4* __restrict__ part_idx,
                 float* __restrict__ out, int rows)
{
    const int row = blockIdx.x;
    const int t = threadIdx.x, wave = t >> 6, lane = t & 63;

    float base = 0.f;
    int fr = INT_MAX, lr = -1, fi = INT_MAX, li = -1;
    #pragma unroll
    for (int s = 0; s < NCHNK; ++s) {
        base += part_sum[row * NCHNK + s];
        int4 v = part_idx[row * NCHNK + s];
        fr = min(fr, v.x); lr = max(lr, v.y);
        fi = min(fi, v.z); li = max(li, v.w);
    }
    if (lr < 0) { fr = 0; lr = HALF - 1; }
    if (li < 0) { fi = 0; li = HALF - 1; }

    const float* Lr = label + (size_t)row * (2 * HALF);
    const float* Li = Lr + HALF;
    const float* Pr = pred + (size_t)row * (2 * HALF);
    const float* Pi = Pr + HALF;

    // extra +1*d^2 outside [first,last] (typically ~0-2 elements per edge)
    float ex = 0.f;
    for (int i = t; i < fr; i += TPB)            { float d = Pr[i] - Lr[i]; ex += d * d; }
    for (int i = lr + 1 + t; i < HALF; i += TPB) { float d = Pr[i] - Lr[i]; ex += d * d; }
    for (int i = t; i < fi; i += TPB)            { float d = Pi[i] - Li[i]; ex += d * d; }
    for (int i = li + 1 + t; i < HALF; i += TPB) { float d = Pi[i] - Li[i]; ex += d * d; }

    #pragma unroll
    for (int off = 32; off > 0; off >>= 1) ex += __shfl_down(ex, off);
    __shared__ float s_ex[4];
    if (lane == 0) s_ex[wave] = ex;
    __syncthreads();
    if (t == 0) {
        const float rv = base + s_ex[0] + s_ex[1] + s_ex[2] + s_ex[3];
        // one device-scope atomic per block (256 total) into out[0], which
        // kernel A zeroed (stream-ordered before this dispatch).
        atomicAdd(out, rv * (1.0f / ((float)HALF * (float)rows)));
    }
}

extern "C" void kernel_launch(void* const* d_in, const int* in_sizes, int n_in,
                              void* d_out, int out_size, void* d_ws, size_t ws_size,
                              hipStream_t stream) {
    const float* pred  = (const float*)d_in[0];
    const float* label = (const float*)d_in[1];
    float* out = (float*)d_out;

    const int rows = in_sizes[0] / (2 * HALF);   // 256
    const int nslots = rows * NCHNK;             // 4096

    float* part_sum = (float*)d_ws;                          // 16 KB
    int4*  part_idx = (int4*)((char*)d_ws + nslots * 4);     // 64 KB (16B-aligned)

    dim3 gridA(NCHNK, rows);
    main_kernel<<<gridA, TPB, 0, stream>>>(pred, label, part_sum, part_idx, out);
    edge_kernel<<<rows, TPB, 0, stream>>>(pred, label, part_sum, part_idx, out, rows);
}

// Round 12
// 28.666 us; speedup vs baseline: 1.0546x; 1.0546x over previous
//
#include <hip/hip_runtime.h>
#include <climits>

// B=256 rows, N=65536, half=32768.
constexpr int HALF = 32768;
constexpr int TPB  = 256;
constexpr int SEG  = 4096;             // elements per (row,seg) per half-stream
constexpr int NSEG = HALF / SEG;       // 8
constexpr int NPASS = SEG / 4 / TPB;   // 4 coalesced float4 passes
constexpr float THRESH = 0.01f;

// ---------------- Kernel A: coalesced streaming pass ----------------
// Per (row,seg): partial unweighted sum (dr^2 + di^2 + 50*dint^2) and
// min/max significant element index for real & imag label halves.
__global__ __launch_bounds__(TPB)
void main_kernel(const float* __restrict__ pred, const float* __restrict__ label,
                 float* __restrict__ part_sum, int4* __restrict__ part_idx)
{
    const int seg = blockIdx.x, row = blockIdx.y;
    const int t = threadIdx.x, wave = t >> 6, lane = t & 63;

    const size_t rb4 = (size_t)row * (size_t)(2 * HALF / 4);
    const int sb4 = seg * (SEG / 4);
    const float4* lr4 = (const float4*)label + rb4 + sb4;
    const float4* li4 = lr4 + (HALF / 4);
    const float4* pr4 = (const float4*)pred + rb4 + sb4;
    const float4* pi4 = pr4 + (HALF / 4);

    float sum = 0.f;
    int minr = INT_MAX, maxr = -1, mini = INT_MAX, maxi = -1;

    #pragma unroll
    for (int p = 0; p < NPASS; ++p) {
        const int v = p * TPB + t;            // lane l -> float4 l : coalesced
        float4 a = lr4[v], b = li4[v], pp = pr4[v], q = pi4[v];
        const int base = seg * SEG + v * 4;   // global element index in half-row

#define STEP(ax, bx, px, qx, idx)                              \
        {                                                      \
            float dr = (px) - (ax), di = (qx) - (bx);          \
            float lint = (ax) * (ax) + (bx) * (bx);            \
            float pint = (px) * (px) + (qx) * (qx);            \
            float dd = pint - lint;                            \
            sum += dr * dr + di * di + 50.f * dd * dd;         \
            if (fabsf(ax) > THRESH) {                          \
                minr = min(minr, (idx)); maxr = max(maxr, (idx)); \
            }                                                  \
            if (fabsf(bx) > THRESH) {                          \
                mini = min(mini, (idx)); maxi = max(maxi, (idx)); \
            }                                                  \
        }
        STEP(a.x, b.x, pp.x, q.x, base + 0)
        STEP(a.y, b.y, pp.y, q.y, base + 1)
        STEP(a.z, b.z, pp.z, q.z, base + 2)
        STEP(a.w, b.w, pp.w, q.w, base + 3)
#undef STEP
    }

    // unordered wave reduce (sum / min / max)
    #pragma unroll
    for (int off = 32; off > 0; off >>= 1) {
        sum  += __shfl_down(sum, off);
        minr  = min(minr, __shfl_down(minr, off));
        maxr  = max(maxr, __shfl_down(maxr, off));
        mini  = min(mini, __shfl_down(mini, off));
        maxi  = max(maxi, __shfl_down(maxi, off));
    }

    __shared__ float s_sum[4];
    __shared__ int s_idx[4][4];
    if (lane == 0) {
        s_sum[wave] = sum;
        s_idx[wave][0] = minr; s_idx[wave][1] = maxr;
        s_idx[wave][2] = mini; s_idx[wave][3] = maxi;
    }
    __syncthreads();
    if (t == 0) {
        float S = 0.f; int mr = INT_MAX, Mr = -1, mi = INT_MAX, Mi = -1;
        #pragma unroll
        for (int w = 0; w < 4; ++w) {
            S += s_sum[w];
            mr = min(mr, s_idx[w][0]); Mr = max(Mr, s_idx[w][1]);
            mi = min(mi, s_idx[w][2]); Mi = max(Mi, s_idx[w][3]);
        }
        const int slot = row * NSEG + seg;
        part_sum[slot] = S;
        part_idx[slot] = make_int4(mr, Mr, mi, Mi);
    }
}

// ---------------- Kernel B: per-row edges + total ----------------
__global__ __launch_bounds__(TPB)
void edge_kernel(const float* __restrict__ pred, const float* __restrict__ label,
                 const float* __restrict__ part_sum, const int4* __restrict__ part_idx,
                 float* __restrict__ row_tot)
{
    const int row = blockIdx.x;
    const int t = threadIdx.x, wave = t >> 6, lane = t & 63;

    float base = 0.f;
    int fr = INT_MAX, lastr = -1, fi = INT_MAX, lasti = -1;
    #pragma unroll
    for (int s = 0; s < NSEG; ++s) {
        base += part_sum[row * NSEG + s];
        int4 v = part_idx[row * NSEG + s];
        fr = min(fr, v.x); lastr = max(lastr, v.y);
        fi = min(fi, v.z); lasti = max(lasti, v.w);
    }
    if (lastr < 0) { fr = 0; lastr = HALF - 1; }
    if (lasti < 0) { fi = 0; lasti = HALF - 1; }

    const float* Lr = label + (size_t)row * (2 * HALF);
    const float* Li = Lr + HALF;
    const float* Pr = pred + (size_t)row * (2 * HALF);
    const float* Pi = Pr + HALF;

    // extra +1*d^2 outside [first,last] (typically ~0-2 elements per edge)
    float ex = 0.f;
    for (int i = t; i < fr; i += TPB)               { float d = Pr[i] - Lr[i]; ex += d * d; }
    for (int i = lastr + 1 + t; i < HALF; i += TPB) { float d = Pr[i] - Lr[i]; ex += d * d; }
    for (int i = t; i < fi; i += TPB)               { float d = Pi[i] - Li[i]; ex += d * d; }
    for (int i = lasti + 1 + t; i < HALF; i += TPB) { float d = Pi[i] - Li[i]; ex += d * d; }

    #pragma unroll
    for (int off = 32; off > 0; off >>= 1) ex += __shfl_down(ex, off);
    __shared__ float s_ex[4];
    if (lane == 0) s_ex[wave] = ex;
    __syncthreads();
    if (t == 0)
        row_tot[row] = base + s_ex[0] + s_ex[1] + s_ex[2] + s_ex[3];
}

// ---------------- Kernel C: final deterministic reduce ----------------
__global__ void finalize_kernel(const float* __restrict__ row_tot,
                                float* __restrict__ out, int rows)
{
    const int t = threadIdx.x;   // 256 threads, 1 block
    float v = 0.f;
    for (int i = t; i < rows; i += 256) v += row_tot[i];
    #pragma unroll
    for (int off = 32; off > 0; off >>= 1) v += __shfl_down(v, off);
    __shared__ float s[4];
    if ((t & 63) == 0) s[t >> 6] = v;
    __syncthreads();
    if (t == 0)
        out[0] = (s[0] + s[1] + s[2] + s[3]) * (1.0f / ((float)HALF * (float)rows));
}

extern "C" void kernel_launch(void* const* d_in, const int* in_sizes, int n_in,
                              void* d_out, int out_size, void* d_ws, size_t ws_size,
                              hipStream_t stream) {
    const float* pred  = (const float*)d_in[0];
    const float* label = (const float*)d_in[1];
    float* out = (float*)d_out;

    const int rows = in_sizes[0] / (2 * HALF);   // 256
    const int nslots = rows * NSEG;              // 2048

    float* part_sum = (float*)d_ws;                          // 2048 floats
    int4*  part_idx = (int4*)((char*)d_ws + nslots * 4);     // 2048 int4 (16B-aligned: 8192 % 16 == 0)
    float* row_tot  = (float*)((char*)d_ws + nslots * 4 + nslots * 16);  // 256 floats

    dim3 gridA(NSEG, rows);
    main_kernel<<<gridA, TPB, 0, stream>>>(pred, label, part_sum, part_idx);
    edge_kernel<<<rows, TPB, 0, stream>>>(pred, label, part_sum, part_idx, row_tot);
    finalize_kernel<<<1, 256, 0, stream>>>(row_tot, out, rows);
}